// Round 2
// baseline (241.362 us; speedup 1.0000x reference)
//
#include <hip/hip_runtime.h>
#include <hip/hip_bf16.h>

// Problem constants (reference: B,K,N,F,H = 20000,10,100000,256,128)
constexpr int B_ = 20000;
constexpr int K_ = 10;
constexpr int N_ = 100000;
constexpr int F_ = 256;
constexpr int H_ = 128;
constexpr int RW = 3 * H_;  // interleaved qkv row width (384 ushorts = 768 B)

typedef __attribute__((ext_vector_type(8))) short bf16x8;
typedef __attribute__((ext_vector_type(4))) float f32x4;
typedef __attribute__((ext_vector_type(4))) unsigned short ushort4v;

__device__ __forceinline__ unsigned short f2bf(float x) {
  unsigned int u = __builtin_bit_cast(unsigned int, x);
  unsigned int r = u + 0x7fffu + ((u >> 16) & 1u);
  return (unsigned short)(r >> 16);
}

__device__ __forceinline__ float bf2f(unsigned int u16) {
  return __builtin_bit_cast(float, u16 << 16);
}

// RNE pack of two f32 -> 2xbf16 in one dword (lo -> [15:0], hi -> [31:16]).
// Same rounding as f2bf on non-NaN inputs; single VALU instr.
__device__ __forceinline__ unsigned int cvt_pk_bf16(float lo, float hi) {
  unsigned int r;
  asm("v_cvt_pk_bf16_f32 %0, %1, %2" : "=v"(r) : "v"(lo), "v"(hi));
  return r;
}

__device__ __forceinline__ float fast_tanh(float x) {
  float e = __expf(2.0f * x);
  return 1.0f - 2.0f * __builtin_amdgcn_rcpf(e + 1.0f);
}

// ---------------------------------------------------------------------------
// Prep: weights -> fragment-major bf16 layout (proven correct; unchanged).
// wat2 chunks (p, ks∈8, c∈8), 512 bf16 each: elem(lane,j) = Wa_p[32ks+8(lane>>4)+j][16c+(lane&15)]
// wbt2 chunks (p, c2∈8, ks2∈4):              elem(lane,j) = Wb_p[32ks2+8(lane>>4)+j][16c2+(lane&15)]
// ---------------------------------------------------------------------------
__global__ __launch_bounds__(256) void prep_kernel(
    const float* __restrict__ W1a, const float* __restrict__ W1b,
    const float* __restrict__ W2a, const float* __restrict__ W2b,
    const float* __restrict__ W3a, const float* __restrict__ W3b,
    unsigned short* __restrict__ wat2, unsigned short* __restrict__ wbt2) {
  const float* Wa[3] = {W1a, W2a, W3a};
  const float* Wb[3] = {W1b, W2b, W3b};
  int g = blockIdx.x * 256 + threadIdx.x;
  if (g < 3 * 64 * 512) {
    int chunk = g >> 9;
    int e = g & 511;
    int lane = e >> 3, j = e & 7;
    int c = chunk & 7;
    int ks = (chunk >> 3) & 7;
    int p = chunk >> 6;
    int k = 32 * ks + 8 * (lane >> 4) + j;
    int h = 16 * c + (lane & 15);
    wat2[g] = f2bf(Wa[p][k * H_ + h]);
  } else {
    int g2 = g - 3 * 64 * 512;
    int chunk = g2 >> 9;
    int e = g2 & 511;
    int lane = e >> 3, j = e & 7;
    int ks2 = chunk & 3;
    int c2 = (chunk >> 2) & 7;
    int p = chunk >> 5;
    int k = 32 * ks2 + 8 * (lane >> 4) + j;
    int h2 = 16 * c2 + (lane & 15);
    wbt2[g2] = f2bf(Wb[p][k * H_ + h2]);
  }
}

// ---------------------------------------------------------------------------
// Projections — ROUND CHANGE: fuse all 3 p's into one pass.
//  * layer-1: acc[3][4]; each bx ds_read feeds 3 MFMAs (reuse across p)
//    -> ds_reads/wave 144 -> 80 (prev round's conflict counter doubled; this
//       reclaims it).
//  * barriers 7 -> 3: stage | all-xs-reads-retired | all-ts-writes-visible.
//    xs is dead after fused layer-1, so ts[3] ALIASES the xs space:
//    union LDS = 3*64*136*2 = 52224 B (~same footprint as before).
//  * pack via v_cvt_pk_bf16_f32 (RNE, identical to f2bf) in stage/tanh/store.
// Wave w owns h-tile w (16 h values); 512 thr / 8 waves; MT=64 nodes.
// ---------------------------------------------------------------------------
constexpr int MT = 64;
constexpr int XS = F_ + 8;  // 264 shorts = 528 B row stride (bank-safe)
constexpr int TS = H_ + 8;  // 136 shorts = 272 B row stride (17x16B slots)

__global__ __launch_bounds__(512, 4) void proj_kernel(
    const float* __restrict__ E,
    const unsigned short* __restrict__ wat2,
    const unsigned short* __restrict__ wbt2,
    unsigned short* __restrict__ qkvI) {
  __shared__ unsigned short lds[3 * MT * TS];  // 52224 B; xs aliases [0,33792)

  const int tid = threadIdx.x;
  const int lane = tid & 63;
  const int w = tid >> 6;    // 0..7 : h-tile owner
  const int l15 = lane & 15;
  const int q = lane >> 4;
  const int row0 = blockIdx.x * MT;

  // ---- stage X tile (fp32 -> bf16), coalesced; clamp OOB rows to N-1
  {
    const float4* Eg = (const float4*)E;
#pragma unroll
    for (int it = 0; it < 8; ++it) {
      int i = tid + 512 * it;
      int r = i >> 6;
      int c4 = i & 63;
      int row = row0 + r;
      if (row >= N_) row = N_ - 1;
      float4 v = Eg[(size_t)row * (F_ / 4) + c4];
      unsigned int lo = cvt_pk_bf16(v.x, v.y);
      unsigned int hi = cvt_pk_bf16(v.z, v.w);
      *(uint2*)&lds[r * XS + c4 * 4] = make_uint2(lo, hi);
    }
  }
  __syncthreads();

  const unsigned short* __restrict__ wa0 = wat2;
  const unsigned short* __restrict__ wa1 = wat2 + 64 * 512;
  const unsigned short* __restrict__ wa2 = wat2 + 2 * 64 * 512;
  const unsigned short* __restrict__ wb0 = wbt2;
  const unsigned short* __restrict__ wb1 = wbt2 + 32 * 512;
  const unsigned short* __restrict__ wb2 = wbt2 + 2 * 32 * 512;

  // ---- fused layer 1 (all p), K=256. acc[p][nt]: h-tile w, node-tile nt.
  f32x4 acc[3][4];
#pragma unroll
  for (int p = 0; p < 3; ++p)
#pragma unroll
    for (int nt = 0; nt < 4; ++nt) acc[p][nt] = (f32x4)0.0f;

#pragma unroll
  for (int ks = 0; ks < 8; ++ks) {
    const int wo = (ks * 8 + w) * 512 + lane * 8;
    bf16x8 af0 = *(const bf16x8*)&wa0[wo];
    bf16x8 af1 = *(const bf16x8*)&wa1[wo];
    bf16x8 af2 = *(const bf16x8*)&wa2[wo];
#pragma unroll
    for (int nt = 0; nt < 4; ++nt) {
      bf16x8 bx = *(const bf16x8*)&lds[(16 * nt + l15) * XS + 32 * ks + 8 * q];
      acc[0][nt] = __builtin_amdgcn_mfma_f32_16x16x32_bf16(af0, bx, acc[0][nt], 0, 0, 0);
      acc[1][nt] = __builtin_amdgcn_mfma_f32_16x16x32_bf16(af1, bx, acc[1][nt], 0, 0, 0);
      acc[2][nt] = __builtin_amdgcn_mfma_f32_16x16x32_bf16(af2, bx, acc[2][nt], 0, 0, 0);
    }
  }

  __syncthreads();  // all xs reads retired; ts[3] may overwrite xs space

  // ---- tanh + pack -> ts[p][node][h] via 8B LDS writes (C->A transpose)
#pragma unroll
  for (int p = 0; p < 3; ++p)
#pragma unroll
    for (int nt = 0; nt < 4; ++nt) {
      unsigned int lo = cvt_pk_bf16(fast_tanh(acc[p][nt][0]), fast_tanh(acc[p][nt][1]));
      unsigned int hi = cvt_pk_bf16(fast_tanh(acc[p][nt][2]), fast_tanh(acc[p][nt][3]));
      // value (h = 16*w+4q+r, node = 16nt+l15)
      *(uint2*)&lds[p * (MT * TS) + (16 * nt + l15) * TS + 16 * w + 4 * q] =
          make_uint2(lo, hi);
    }
  __syncthreads();

  // ---- fused layer 2 (all p), K=128
  f32x4 ac2[3][4];
#pragma unroll
  for (int p = 0; p < 3; ++p)
#pragma unroll
    for (int nt = 0; nt < 4; ++nt) ac2[p][nt] = (f32x4)0.0f;

#pragma unroll
  for (int ks2 = 0; ks2 < 4; ++ks2) {
    const int wo = (w * 4 + ks2) * 512 + lane * 8;
    bf16x8 ab0 = *(const bf16x8*)&wb0[wo];
    bf16x8 ab1 = *(const bf16x8*)&wb1[wo];
    bf16x8 ab2 = *(const bf16x8*)&wb2[wo];
#pragma unroll
    for (int nt = 0; nt < 4; ++nt) {
      const int to = (16 * nt + l15) * TS + 32 * ks2 + 8 * q;
      bf16x8 bt0 = *(const bf16x8*)&lds[to];
      bf16x8 bt1 = *(const bf16x8*)&lds[(MT * TS) + to];
      bf16x8 bt2 = *(const bf16x8*)&lds[2 * (MT * TS) + to];
      ac2[0][nt] = __builtin_amdgcn_mfma_f32_16x16x32_bf16(ab0, bt0, ac2[0][nt], 0, 0, 0);
      ac2[1][nt] = __builtin_amdgcn_mfma_f32_16x16x32_bf16(ab1, bt1, ac2[1][nt], 0, 0, 0);
      ac2[2][nt] = __builtin_amdgcn_mfma_f32_16x16x32_bf16(ab2, bt2, ac2[2][nt], 0, 0, 0);
    }
  }

  // ---- store qkv^T: col=node, rows h2 consecutive -> 8B contiguous stores
#pragma unroll
  for (int p = 0; p < 3; ++p)
#pragma unroll
    for (int nt = 0; nt < 4; ++nt) {
      int n = row0 + 16 * nt + l15;
      if (n < N_) {
        unsigned int lo = cvt_pk_bf16(ac2[p][nt][0], ac2[p][nt][1]);
        unsigned int hi = cvt_pk_bf16(ac2[p][nt][2], ac2[p][nt][3]);
        *(uint2*)&qkvI[(size_t)n * RW + p * H_ + 16 * w + 4 * q] =
            make_uint2(lo, hi);
      }
    }
}

// ---------------------------------------------------------------------------
// Phase 2: one WAVE per batch node, gathering from interleaved qkvI
// (768 B contiguous per neighbor). No LDS, no barriers. (Unchanged.)
// ---------------------------------------------------------------------------
__global__ __launch_bounds__(256) void agg_kernel(
    const int* __restrict__ nbr,
    const unsigned short* __restrict__ qkvI,
    float* __restrict__ out) {
  const int lane = threadIdx.x & 63;
  const int wv = threadIdx.x >> 6;
  const int b = blockIdx.x * 4 + wv;
  const int l15 = lane & 15;
  const int kg = lane >> 4;

  const int ni = nbr[b * K_ + (l15 < K_ ? l15 : 0)];
  const size_t nbase = (size_t)ni * RW;

  // scores[i][j] = q_i . k_j
  f32x4 sc = (f32x4)0.0f;
#pragma unroll
  for (int k = 0; k < 4; ++k) {
    const int off = k * 32 + kg * 8;
    bf16x8 qf = *(const bf16x8*)&qkvI[nbase + off];
    bf16x8 kf = *(const bf16x8*)&qkvI[nbase + H_ + off];
    sc = __builtin_amdgcn_mfma_f32_16x16x32_bf16(qf, kf, sc, 0, 0, 0);
  }

  if (l15 >= K_) {
#pragma unroll
    for (int r = 0; r < 4; ++r) sc[r] = -3.0e38f;
  }

  float mx[4], e[4], sm[4];
#pragma unroll
  for (int r = 0; r < 4; ++r) mx[r] = sc[r];
#pragma unroll
  for (int st = 1; st < 16; st <<= 1)
#pragma unroll
    for (int r = 0; r < 4; ++r) mx[r] = fmaxf(mx[r], __shfl_xor(mx[r], st, 16));
#pragma unroll
  for (int r = 0; r < 4; ++r) { e[r] = __expf(sc[r] - mx[r]); sm[r] = e[r]; }
#pragma unroll
  for (int st = 1; st < 16; st <<= 1)
#pragma unroll
    for (int r = 0; r < 4; ++r) sm[r] += __shfl_xor(sm[r], st, 16);

  float cs = 0.0f;
#pragma unroll
  for (int r = 0; r < 4; ++r) {
    float a = e[r] * __builtin_amdgcn_rcpf(sm[r]);
    if (kg * 4 + r >= K_) a = 0.0f;
    cs += a;
  }
  cs += __shfl_xor(cs, 16, 64);
  cs += __shfl_xor(cs, 32, 64);

  float o0 = 0.0f, o1 = 0.0f;
#pragma unroll
  for (int j = 0; j < K_; ++j) {
    const float cj = __shfl(cs, j, 64);
    const int nj = __shfl(ni, j, 64);
    const unsigned int v2 =
        *(const unsigned int*)&qkvI[(size_t)nj * RW + 2 * H_ + 2 * lane];
    o0 = fmaf(cj, bf2f(v2 & 0xffffu), o0);
    o1 = fmaf(cj, bf2f(v2 >> 16), o1);
  }
  *(float2*)&out[(size_t)b * H_ + 2 * lane] = make_float2(o0, o1);
}

extern "C" void kernel_launch(void* const* d_in, const int* in_sizes, int n_in,
                              void* d_out, int out_size, void* d_ws, size_t ws_size,
                              hipStream_t stream) {
  const int* nbr = (const int*)d_in[0];
  const float* E = (const float*)d_in[1];
  const float* W1a = (const float*)d_in[2];
  const float* W1b = (const float*)d_in[3];
  const float* W2a = (const float*)d_in[4];
  const float* W2b = (const float*)d_in[5];
  const float* W3a = (const float*)d_in[6];
  const float* W3b = (const float*)d_in[7];
  float* out = (float*)d_out;

  // workspace: qkvI [N][384] bf16 interleaved = 76.8 MB, then frag-major weights
  unsigned short* qkvI = (unsigned short*)d_ws;
  unsigned short* wat2 = qkvI + (size_t)N_ * RW;
  unsigned short* wbt2 = wat2 + (size_t)3 * 64 * 512;

  prep_kernel<<<(3 * 64 * 512 + 3 * 32 * 512) / 256, 256, 0, stream>>>(
      W1a, W1b, W2a, W2b, W3a, W3b, wat2, wbt2);
  proj_kernel<<<(N_ + MT - 1) / MT, 512, 0, stream>>>(E, wat2, wbt2, qkvI);
  agg_kernel<<<B_ / 4, 256, 0, stream>>>(nbr, qkvI, out);
}

// Round 4
// 237.157 us; speedup vs baseline: 1.0177x; 1.0177x over previous
//
#include <hip/hip_runtime.h>
#include <hip/hip_bf16.h>

// Problem constants (reference: B,K,N,F,H = 20000,10,100000,256,128)
constexpr int B_ = 20000;
constexpr int K_ = 10;
constexpr int N_ = 100000;
constexpr int F_ = 256;
constexpr int H_ = 128;
constexpr int RW = 3 * H_;  // interleaved qkv row width (384 ushorts = 768 B)

typedef __attribute__((ext_vector_type(8))) short bf16x8;
typedef __attribute__((ext_vector_type(4))) float f32x4;
typedef __attribute__((ext_vector_type(4))) unsigned short ushort4v;

__device__ __forceinline__ unsigned short f2bf(float x) {
  unsigned int u = __builtin_bit_cast(unsigned int, x);
  unsigned int r = u + 0x7fffu + ((u >> 16) & 1u);
  return (unsigned short)(r >> 16);
}

__device__ __forceinline__ float bf2f(unsigned int u16) {
  return __builtin_bit_cast(float, u16 << 16);
}

// RNE pack of two f32 -> 2xbf16 in one dword (lo -> [15:0], hi -> [31:16]).
__device__ __forceinline__ unsigned int cvt_pk_bf16(float lo, float hi) {
  unsigned int r;
  asm("v_cvt_pk_bf16_f32 %0, %1, %2" : "=v"(r) : "v"(lo), "v"(hi));
  return r;
}

__device__ __forceinline__ float fast_tanh(float x) {
  float e = __expf(2.0f * x);
  return 1.0f - 2.0f * __builtin_amdgcn_rcpf(e + 1.0f);
}

// ---------------------------------------------------------------------------
// Prep: weights -> fragment-major bf16 layout (proven correct; unchanged).
// wat2 chunks (p, ks∈8, c∈8), 512 bf16 each: elem(lane,j) = Wa_p[32ks+8(lane>>4)+j][16c+(lane&15)]
// wbt2 chunks (p, c2∈8, ks2∈4):              elem(lane,j) = Wb_p[32ks2+8(lane>>4)+j][16c2+(lane&15)]
// ---------------------------------------------------------------------------
__global__ __launch_bounds__(256) void prep_kernel(
    const float* __restrict__ W1a, const float* __restrict__ W1b,
    const float* __restrict__ W2a, const float* __restrict__ W2b,
    const float* __restrict__ W3a, const float* __restrict__ W3b,
    unsigned short* __restrict__ wat2, unsigned short* __restrict__ wbt2) {
  const float* Wa[3] = {W1a, W2a, W3a};
  const float* Wb[3] = {W1b, W2b, W3b};
  int g = blockIdx.x * 256 + threadIdx.x;
  if (g < 3 * 64 * 512) {
    int chunk = g >> 9;
    int e = g & 511;
    int lane = e >> 3, j = e & 7;
    int c = chunk & 7;
    int ks = (chunk >> 3) & 7;
    int p = chunk >> 6;
    int k = 32 * ks + 8 * (lane >> 4) + j;
    int h = 16 * c + (lane & 15);
    wat2[g] = f2bf(Wa[p][k * H_ + h]);
  } else {
    int g2 = g - 3 * 64 * 512;
    int chunk = g2 >> 9;
    int e = g2 & 511;
    int lane = e >> 3, j = e & 7;
    int ks2 = chunk & 3;
    int c2 = (chunk >> 2) & 7;
    int p = chunk >> 5;
    int k = 32 * ks2 + 8 * (lane >> 4) + j;
    int h2 = 16 * c2 + (lane & 15);
    wbt2[g2] = f2bf(Wb[p][k * H_ + h2]);
  }
}

// ---------------------------------------------------------------------------
// Projections — R4: R3 geometry (MT=32, 4 waves, 2x2 register blocking,
// 25.6 KB LDS -> 6 blocks/CU) with the R3 failure suspect REMOVED:
// no min-waves-per-EU clamp in __launch_bounds__ (R3's (256,6) forced
// VGPR<=85 -> spill/launch failure -> garbage workspace -> NaN).
// Natural VGPR (~60-70) should allow 6 blocks anyway (LDS-limited).
// OOB guards re-added as cheap insurance.
// ---------------------------------------------------------------------------
constexpr int MT = 32;
constexpr int XS = F_ + 8;  // 264 shorts = 528 B row stride (2-way max, free)
constexpr int TS = H_ + 8;  // 136 shorts = 272 B row stride

__global__ __launch_bounds__(256) void proj_kernel(
    const float* __restrict__ E,
    const unsigned short* __restrict__ wat2,
    const unsigned short* __restrict__ wbt2,
    unsigned short* __restrict__ qkvI) {
  __shared__ unsigned short xs[MT * XS];  // 16896 B
  __shared__ unsigned short ts[MT * TS];  // 8704 B

  const int tid = threadIdx.x;
  const int lane = tid & 63;
  const int w = tid >> 6;    // 0..3 : owns h-tiles {2w, 2w+1}
  const int l15 = lane & 15;
  const int q = lane >> 4;
  const int row0 = blockIdx.x * MT;

  // ---- stage X tile (fp32 -> bf16), coalesced; clamp OOB rows (insurance)
  {
    const float4* Eg = (const float4*)E;
#pragma unroll
    for (int it = 0; it < 8; ++it) {
      int i = tid + 256 * it;
      int r = i >> 6;
      int c4 = i & 63;
      int row = row0 + r;
      if (row >= N_) row = N_ - 1;
      float4 v = Eg[(size_t)row * (F_ / 4) + c4];
      unsigned int lo = cvt_pk_bf16(v.x, v.y);
      unsigned int hi = cvt_pk_bf16(v.z, v.w);
      *(uint2*)&xs[r * XS + c4 * 4] = make_uint2(lo, hi);
    }
  }
  __syncthreads();

  for (int p = 0; p < 3; ++p) {
    const unsigned short* __restrict__ wa = wat2 + p * (64 * 512);
    const unsigned short* __restrict__ wb = wbt2 + p * (32 * 512);

    // ---- layer 1, K=256. acc[i][j]: h-tile 2w+i, node-tile j.
    f32x4 acc[2][2];
#pragma unroll
    for (int i = 0; i < 2; ++i)
#pragma unroll
      for (int j = 0; j < 2; ++j) acc[i][j] = (f32x4)0.0f;

#pragma unroll
    for (int ks = 0; ks < 8; ++ks) {
      bf16x8 af0 = *(const bf16x8*)&wa[(ks * 8 + 2 * w) * 512 + lane * 8];
      bf16x8 af1 = *(const bf16x8*)&wa[(ks * 8 + 2 * w + 1) * 512 + lane * 8];
      bf16x8 bx0 = *(const bf16x8*)&xs[(l15)*XS + 32 * ks + 8 * q];
      bf16x8 bx1 = *(const bf16x8*)&xs[(16 + l15) * XS + 32 * ks + 8 * q];
      acc[0][0] = __builtin_amdgcn_mfma_f32_16x16x32_bf16(af0, bx0, acc[0][0], 0, 0, 0);
      acc[0][1] = __builtin_amdgcn_mfma_f32_16x16x32_bf16(af0, bx1, acc[0][1], 0, 0, 0);
      acc[1][0] = __builtin_amdgcn_mfma_f32_16x16x32_bf16(af1, bx0, acc[1][0], 0, 0, 0);
      acc[1][1] = __builtin_amdgcn_mfma_f32_16x16x32_bf16(af1, bx1, acc[1][1], 0, 0, 0);
    }

    // ---- tanh + pack -> ts[node][h] via 8B LDS writes (C->A transpose)
    __syncthreads();  // prior p's ts reads complete
#pragma unroll
    for (int i = 0; i < 2; ++i)
#pragma unroll
      for (int j = 0; j < 2; ++j) {
        unsigned int lo = cvt_pk_bf16(fast_tanh(acc[i][j][0]), fast_tanh(acc[i][j][1]));
        unsigned int hi = cvt_pk_bf16(fast_tanh(acc[i][j][2]), fast_tanh(acc[i][j][3]));
        // value (h = 16*(2w+i)+4q+r, node = 16j+l15)
        *(uint2*)&ts[(16 * j + l15) * TS + 16 * (2 * w + i) + 4 * q] =
            make_uint2(lo, hi);
      }
    __syncthreads();

    // ---- layer 2, K=128
    f32x4 ac2[2][2];
#pragma unroll
    for (int i = 0; i < 2; ++i)
#pragma unroll
      for (int j = 0; j < 2; ++j) ac2[i][j] = (f32x4)0.0f;

#pragma unroll
    for (int ks2 = 0; ks2 < 4; ++ks2) {
      bf16x8 ab0 = *(const bf16x8*)&wb[((2 * w) * 4 + ks2) * 512 + lane * 8];
      bf16x8 ab1 = *(const bf16x8*)&wb[((2 * w + 1) * 4 + ks2) * 512 + lane * 8];
      bf16x8 bt0 = *(const bf16x8*)&ts[(l15)*TS + 32 * ks2 + 8 * q];
      bf16x8 bt1 = *(const bf16x8*)&ts[(16 + l15) * TS + 32 * ks2 + 8 * q];
      ac2[0][0] = __builtin_amdgcn_mfma_f32_16x16x32_bf16(ab0, bt0, ac2[0][0], 0, 0, 0);
      ac2[0][1] = __builtin_amdgcn_mfma_f32_16x16x32_bf16(ab0, bt1, ac2[0][1], 0, 0, 0);
      ac2[1][0] = __builtin_amdgcn_mfma_f32_16x16x32_bf16(ab1, bt0, ac2[1][0], 0, 0, 0);
      ac2[1][1] = __builtin_amdgcn_mfma_f32_16x16x32_bf16(ab1, bt1, ac2[1][1], 0, 0, 0);
    }

    // ---- store qkv^T: col=node, rows h2 consecutive -> 8B contiguous stores
#pragma unroll
    for (int i = 0; i < 2; ++i)
#pragma unroll
      for (int j = 0; j < 2; ++j) {
        int n = row0 + 16 * j + l15;
        if (n < N_) {
          unsigned int lo = cvt_pk_bf16(ac2[i][j][0], ac2[i][j][1]);
          unsigned int hi = cvt_pk_bf16(ac2[i][j][2], ac2[i][j][3]);
          *(uint2*)&qkvI[(size_t)n * RW + p * H_ + 16 * (2 * w + i) + 4 * q] =
              make_uint2(lo, hi);
        }
      }
  }
}

// ---------------------------------------------------------------------------
// Phase 2: one WAVE per batch node, gathering from interleaved qkvI
// (768 B contiguous per neighbor). No LDS, no barriers. (Unchanged.)
// ---------------------------------------------------------------------------
__global__ __launch_bounds__(256) void agg_kernel(
    const int* __restrict__ nbr,
    const unsigned short* __restrict__ qkvI,
    float* __restrict__ out) {
  const int lane = threadIdx.x & 63;
  const int wv = threadIdx.x >> 6;
  const int b = blockIdx.x * 4 + wv;
  const int l15 = lane & 15;
  const int kg = lane >> 4;

  const int ni = nbr[b * K_ + (l15 < K_ ? l15 : 0)];
  const size_t nbase = (size_t)ni * RW;

  // scores[i][j] = q_i . k_j
  f32x4 sc = (f32x4)0.0f;
#pragma unroll
  for (int k = 0; k < 4; ++k) {
    const int off = k * 32 + kg * 8;
    bf16x8 qf = *(const bf16x8*)&qkvI[nbase + off];
    bf16x8 kf = *(const bf16x8*)&qkvI[nbase + H_ + off];
    sc = __builtin_amdgcn_mfma_f32_16x16x32_bf16(qf, kf, sc, 0, 0, 0);
  }

  if (l15 >= K_) {
#pragma unroll
    for (int r = 0; r < 4; ++r) sc[r] = -3.0e38f;
  }

  float mx[4], e[4], sm[4];
#pragma unroll
  for (int r = 0; r < 4; ++r) mx[r] = sc[r];
#pragma unroll
  for (int st = 1; st < 16; st <<= 1)
#pragma unroll
    for (int r = 0; r < 4; ++r) mx[r] = fmaxf(mx[r], __shfl_xor(mx[r], st, 16));
#pragma unroll
  for (int r = 0; r < 4; ++r) { e[r] = __expf(sc[r] - mx[r]); sm[r] = e[r]; }
#pragma unroll
  for (int st = 1; st < 16; st <<= 1)
#pragma unroll
    for (int r = 0; r < 4; ++r) sm[r] += __shfl_xor(sm[r], st, 16);

  float cs = 0.0f;
#pragma unroll
  for (int r = 0; r < 4; ++r) {
    float a = e[r] * __builtin_amdgcn_rcpf(sm[r]);
    if (kg * 4 + r >= K_) a = 0.0f;
    cs += a;
  }
  cs += __shfl_xor(cs, 16, 64);
  cs += __shfl_xor(cs, 32, 64);

  float o0 = 0.0f, o1 = 0.0f;
#pragma unroll
  for (int j = 0; j < K_; ++j) {
    const float cj = __shfl(cs, j, 64);
    const int nj = __shfl(ni, j, 64);
    const unsigned int v2 =
        *(const unsigned int*)&qkvI[(size_t)nj * RW + 2 * H_ + 2 * lane];
    o0 = fmaf(cj, bf2f(v2 & 0xffffu), o0);
    o1 = fmaf(cj, bf2f(v2 >> 16), o1);
  }
  *(float2*)&out[(size_t)b * H_ + 2 * lane] = make_float2(o0, o1);
}

extern "C" void kernel_launch(void* const* d_in, const int* in_sizes, int n_in,
                              void* d_out, int out_size, void* d_ws, size_t ws_size,
                              hipStream_t stream) {
  const int* nbr = (const int*)d_in[0];
  const float* E = (const float*)d_in[1];
  const float* W1a = (const float*)d_in[2];
  const float* W1b = (const float*)d_in[3];
  const float* W2a = (const float*)d_in[4];
  const float* W2b = (const float*)d_in[5];
  const float* W3a = (const float*)d_in[6];
  const float* W3b = (const float*)d_in[7];
  float* out = (float*)d_out;

  // workspace: qkvI [N][384] bf16 interleaved = 76.8 MB, then frag-major weights
  unsigned short* qkvI = (unsigned short*)d_ws;
  unsigned short* wat2 = qkvI + (size_t)N_ * RW;
  unsigned short* wbt2 = wat2 + (size_t)3 * 64 * 512;

  prep_kernel<<<(3 * 64 * 512 + 3 * 32 * 512) / 256, 256, 0, stream>>>(
      W1a, W1b, W2a, W2b, W3a, W3b, wat2, wbt2);
  proj_kernel<<<N_ / MT, 256, 0, stream>>>(E, wat2, wbt2, qkvI);
  agg_kernel<<<B_ / 4, 256, 0, stream>>>(nbr, qkvI, out);
}

// Round 5
// 236.384 us; speedup vs baseline: 1.0211x; 1.0033x over previous
//
#include <hip/hip_runtime.h>
#include <hip/hip_bf16.h>

// Problem constants (reference: B,K,N,F,H = 20000,10,100000,256,128)
constexpr int B_ = 20000;
constexpr int K_ = 10;
constexpr int N_ = 100000;
constexpr int F_ = 256;
constexpr int H_ = 128;
constexpr int RW = 3 * H_;  // interleaved qkv row width (384 ushorts = 768 B)

typedef __attribute__((ext_vector_type(8))) short bf16x8;
typedef __attribute__((ext_vector_type(4))) float f32x4;
typedef __attribute__((ext_vector_type(4))) unsigned short ushort4v;

__device__ __forceinline__ unsigned short f2bf(float x) {
  unsigned int u = __builtin_bit_cast(unsigned int, x);
  unsigned int r = u + 0x7fffu + ((u >> 16) & 1u);
  return (unsigned short)(r >> 16);
}

__device__ __forceinline__ float bf2f(unsigned int u16) {
  return __builtin_bit_cast(float, u16 << 16);
}

// RNE pack of two f32 -> 2xbf16 in one dword (lo -> [15:0], hi -> [31:16]).
__device__ __forceinline__ unsigned int cvt_pk_bf16(float lo, float hi) {
  unsigned int r;
  asm("v_cvt_pk_bf16_f32 %0, %1, %2" : "=v"(r) : "v"(lo), "v"(hi));
  return r;
}

__device__ __forceinline__ float fast_tanh(float x) {
  float e = __expf(2.0f * x);
  return 1.0f - 2.0f * __builtin_amdgcn_rcpf(e + 1.0f);
}

// ---------------------------------------------------------------------------
// Prep: weights -> fragment-major bf16 layout (proven correct; unchanged).
// wat2 chunks (p, ks∈8, c∈8), 512 bf16 each: elem(lane,j) = Wa_p[32ks+8(lane>>4)+j][16c+(lane&15)]
// wbt2 chunks (p, c2∈8, ks2∈4):              elem(lane,j) = Wb_p[32ks2+8(lane>>4)+j][16c2+(lane&15)]
// ---------------------------------------------------------------------------
__global__ __launch_bounds__(256) void prep_kernel(
    const float* __restrict__ W1a, const float* __restrict__ W1b,
    const float* __restrict__ W2a, const float* __restrict__ W2b,
    const float* __restrict__ W3a, const float* __restrict__ W3b,
    unsigned short* __restrict__ wat2, unsigned short* __restrict__ wbt2) {
  const float* Wa[3] = {W1a, W2a, W3a};
  const float* Wb[3] = {W1b, W2b, W3b};
  int g = blockIdx.x * 256 + threadIdx.x;
  if (g < 3 * 64 * 512) {
    int chunk = g >> 9;
    int e = g & 511;
    int lane = e >> 3, j = e & 7;
    int c = chunk & 7;
    int ks = (chunk >> 3) & 7;
    int p = chunk >> 6;
    int k = 32 * ks + 8 * (lane >> 4) + j;
    int h = 16 * c + (lane & 15);
    wat2[g] = f2bf(Wa[p][k * H_ + h]);
  } else {
    int g2 = g - 3 * 64 * 512;
    int chunk = g2 >> 9;
    int e = g2 & 511;
    int lane = e >> 3, j = e & 7;
    int ks2 = chunk & 3;
    int c2 = (chunk >> 2) & 7;
    int p = chunk >> 5;
    int k = 32 * ks2 + 8 * (lane >> 4) + j;
    int h2 = 16 * c2 + (lane & 15);
    wbt2[g2] = f2bf(Wb[p][k * H_ + h2]);
  }
}

// ---------------------------------------------------------------------------
// Projections — R5: R4 geometry (PASSING: MT=32, 4 waves, 2x2 blocking)
// + ILP fix. Diagnosis: VGPR_Count=40 proved the compiler serialized the
// L2 weight loads (only ~4 in flight of 16 needed) -> each MFMA group eats
// L2 latency; occupancy 50->56% didn't help because every wave stalls at
// the same waits. Change: explicit register preload of ALL layer-1 weight
// frags (af[2][8], 16 loads back-to-back in flight) before the MFMA loop,
// and layer-2 frags (ab[2][4]) issued right after layer-1 MFMAs so they
// cross L2 during tanh + both barriers. Fully-unrolled static indexing
// (no scratch). No min-waves clamp (R3 lesson).
// ---------------------------------------------------------------------------
constexpr int MT = 32;
constexpr int XS = F_ + 8;  // 264 shorts = 528 B row stride (2-way max, free)
constexpr int TS = H_ + 8;  // 136 shorts = 272 B row stride

__global__ __launch_bounds__(256) void proj_kernel(
    const float* __restrict__ E,
    const unsigned short* __restrict__ wat2,
    const unsigned short* __restrict__ wbt2,
    unsigned short* __restrict__ qkvI) {
  __shared__ unsigned short xs[MT * XS];  // 16896 B
  __shared__ unsigned short ts[MT * TS];  // 8704 B

  const int tid = threadIdx.x;
  const int lane = tid & 63;
  const int w = tid >> 6;    // 0..3 : owns h-tiles {2w, 2w+1}
  const int l15 = lane & 15;
  const int q = lane >> 4;
  const int row0 = blockIdx.x * MT;

  // ---- stage X tile (fp32 -> bf16), coalesced; clamp OOB rows (insurance)
  {
    const float4* Eg = (const float4*)E;
#pragma unroll
    for (int it = 0; it < 8; ++it) {
      int i = tid + 256 * it;
      int r = i >> 6;
      int c4 = i & 63;
      int row = row0 + r;
      if (row >= N_) row = N_ - 1;
      float4 v = Eg[(size_t)row * (F_ / 4) + c4];
      unsigned int lo = cvt_pk_bf16(v.x, v.y);
      unsigned int hi = cvt_pk_bf16(v.z, v.w);
      *(uint2*)&xs[r * XS + c4 * 4] = make_uint2(lo, hi);
    }
  }
  __syncthreads();

  for (int p = 0; p < 3; ++p) {
    const unsigned short* __restrict__ wa = wat2 + p * (64 * 512);
    const unsigned short* __restrict__ wb = wbt2 + p * (32 * 512);

    // ---- preload ALL layer-1 weight fragments: 16 dwordx4 loads in flight.
    bf16x8 af[2][8];
#pragma unroll
    for (int ks = 0; ks < 8; ++ks) {
      af[0][ks] = *(const bf16x8*)&wa[(ks * 8 + 2 * w) * 512 + lane * 8];
      af[1][ks] = *(const bf16x8*)&wa[(ks * 8 + 2 * w + 1) * 512 + lane * 8];
    }

    // ---- layer 1, K=256. acc[i][j]: h-tile 2w+i, node-tile j.
    f32x4 acc[2][2];
#pragma unroll
    for (int i = 0; i < 2; ++i)
#pragma unroll
      for (int j = 0; j < 2; ++j) acc[i][j] = (f32x4)0.0f;

#pragma unroll
    for (int ks = 0; ks < 8; ++ks) {
      bf16x8 bx0 = *(const bf16x8*)&xs[(l15)*XS + 32 * ks + 8 * q];
      bf16x8 bx1 = *(const bf16x8*)&xs[(16 + l15) * XS + 32 * ks + 8 * q];
      acc[0][0] = __builtin_amdgcn_mfma_f32_16x16x32_bf16(af[0][ks], bx0, acc[0][0], 0, 0, 0);
      acc[0][1] = __builtin_amdgcn_mfma_f32_16x16x32_bf16(af[0][ks], bx1, acc[0][1], 0, 0, 0);
      acc[1][0] = __builtin_amdgcn_mfma_f32_16x16x32_bf16(af[1][ks], bx0, acc[1][0], 0, 0, 0);
      acc[1][1] = __builtin_amdgcn_mfma_f32_16x16x32_bf16(af[1][ks], bx1, acc[1][1], 0, 0, 0);
    }

    // ---- issue layer-2 weight preload NOW: lands during tanh + barriers.
    bf16x8 ab[2][4];
#pragma unroll
    for (int ks2 = 0; ks2 < 4; ++ks2) {
      ab[0][ks2] = *(const bf16x8*)&wb[((2 * w) * 4 + ks2) * 512 + lane * 8];
      ab[1][ks2] = *(const bf16x8*)&wb[((2 * w + 1) * 4 + ks2) * 512 + lane * 8];
    }

    // ---- tanh + pack -> ts[node][h] via 8B LDS writes (C->A transpose)
    __syncthreads();  // prior p's ts reads complete
#pragma unroll
    for (int i = 0; i < 2; ++i)
#pragma unroll
      for (int j = 0; j < 2; ++j) {
        unsigned int lo = cvt_pk_bf16(fast_tanh(acc[i][j][0]), fast_tanh(acc[i][j][1]));
        unsigned int hi = cvt_pk_bf16(fast_tanh(acc[i][j][2]), fast_tanh(acc[i][j][3]));
        // value (h = 16*(2w+i)+4q+r, node = 16j+l15)
        *(uint2*)&ts[(16 * j + l15) * TS + 16 * (2 * w + i) + 4 * q] =
            make_uint2(lo, hi);
      }
    __syncthreads();

    // ---- layer 2, K=128 (weights already in registers)
    f32x4 ac2[2][2];
#pragma unroll
    for (int i = 0; i < 2; ++i)
#pragma unroll
      for (int j = 0; j < 2; ++j) ac2[i][j] = (f32x4)0.0f;

#pragma unroll
    for (int ks2 = 0; ks2 < 4; ++ks2) {
      bf16x8 bt0 = *(const bf16x8*)&ts[(l15)*TS + 32 * ks2 + 8 * q];
      bf16x8 bt1 = *(const bf16x8*)&ts[(16 + l15) * TS + 32 * ks2 + 8 * q];
      ac2[0][0] = __builtin_amdgcn_mfma_f32_16x16x32_bf16(ab[0][ks2], bt0, ac2[0][0], 0, 0, 0);
      ac2[0][1] = __builtin_amdgcn_mfma_f32_16x16x32_bf16(ab[0][ks2], bt1, ac2[0][1], 0, 0, 0);
      ac2[1][0] = __builtin_amdgcn_mfma_f32_16x16x32_bf16(ab[1][ks2], bt0, ac2[1][0], 0, 0, 0);
      ac2[1][1] = __builtin_amdgcn_mfma_f32_16x16x32_bf16(ab[1][ks2], bt1, ac2[1][1], 0, 0, 0);
    }

    // ---- store qkv^T: col=node, rows h2 consecutive -> 8B contiguous stores
#pragma unroll
    for (int i = 0; i < 2; ++i)
#pragma unroll
      for (int j = 0; j < 2; ++j) {
        int n = row0 + 16 * j + l15;
        if (n < N_) {
          unsigned int lo = cvt_pk_bf16(ac2[i][j][0], ac2[i][j][1]);
          unsigned int hi = cvt_pk_bf16(ac2[i][j][2], ac2[i][j][3]);
          *(uint2*)&qkvI[(size_t)n * RW + p * H_ + 16 * (2 * w + i) + 4 * q] =
              make_uint2(lo, hi);
        }
      }
  }
}

// ---------------------------------------------------------------------------
// Phase 2: one WAVE per batch node, gathering from interleaved qkvI
// (768 B contiguous per neighbor). No LDS, no barriers. (Unchanged.)
// ---------------------------------------------------------------------------
__global__ __launch_bounds__(256) void agg_kernel(
    const int* __restrict__ nbr,
    const unsigned short* __restrict__ qkvI,
    float* __restrict__ out) {
  const int lane = threadIdx.x & 63;
  const int wv = threadIdx.x >> 6;
  const int b = blockIdx.x * 4 + wv;
  const int l15 = lane & 15;
  const int kg = lane >> 4;

  const int ni = nbr[b * K_ + (l15 < K_ ? l15 : 0)];
  const size_t nbase = (size_t)ni * RW;

  // scores[i][j] = q_i . k_j
  f32x4 sc = (f32x4)0.0f;
#pragma unroll
  for (int k = 0; k < 4; ++k) {
    const int off = k * 32 + kg * 8;
    bf16x8 qf = *(const bf16x8*)&qkvI[nbase + off];
    bf16x8 kf = *(const bf16x8*)&qkvI[nbase + H_ + off];
    sc = __builtin_amdgcn_mfma_f32_16x16x32_bf16(qf, kf, sc, 0, 0, 0);
  }

  if (l15 >= K_) {
#pragma unroll
    for (int r = 0; r < 4; ++r) sc[r] = -3.0e38f;
  }

  float mx[4], e[4], sm[4];
#pragma unroll
  for (int r = 0; r < 4; ++r) mx[r] = sc[r];
#pragma unroll
  for (int st = 1; st < 16; st <<= 1)
#pragma unroll
    for (int r = 0; r < 4; ++r) mx[r] = fmaxf(mx[r], __shfl_xor(mx[r], st, 16));
#pragma unroll
  for (int r = 0; r < 4; ++r) { e[r] = __expf(sc[r] - mx[r]); sm[r] = e[r]; }
#pragma unroll
  for (int st = 1; st < 16; st <<= 1)
#pragma unroll
    for (int r = 0; r < 4; ++r) sm[r] += __shfl_xor(sm[r], st, 16);

  float cs = 0.0f;
#pragma unroll
  for (int r = 0; r < 4; ++r) {
    float a = e[r] * __builtin_amdgcn_rcpf(sm[r]);
    if (kg * 4 + r >= K_) a = 0.0f;
    cs += a;
  }
  cs += __shfl_xor(cs, 16, 64);
  cs += __shfl_xor(cs, 32, 64);

  float o0 = 0.0f, o1 = 0.0f;
#pragma unroll
  for (int j = 0; j < K_; ++j) {
    const float cj = __shfl(cs, j, 64);
    const int nj = __shfl(ni, j, 64);
    const unsigned int v2 =
        *(const unsigned int*)&qkvI[(size_t)nj * RW + 2 * H_ + 2 * lane];
    o0 = fmaf(cj, bf2f(v2 & 0xffffu), o0);
    o1 = fmaf(cj, bf2f(v2 >> 16), o1);
  }
  *(float2*)&out[(size_t)b * H_ + 2 * lane] = make_float2(o0, o1);
}

extern "C" void kernel_launch(void* const* d_in, const int* in_sizes, int n_in,
                              void* d_out, int out_size, void* d_ws, size_t ws_size,
                              hipStream_t stream) {
  const int* nbr = (const int*)d_in[0];
  const float* E = (const float*)d_in[1];
  const float* W1a = (const float*)d_in[2];
  const float* W1b = (const float*)d_in[3];
  const float* W2a = (const float*)d_in[4];
  const float* W2b = (const float*)d_in[5];
  const float* W3a = (const float*)d_in[6];
  const float* W3b = (const float*)d_in[7];
  float* out = (float*)d_out;

  // workspace: qkvI [N][384] bf16 interleaved = 76.8 MB, then frag-major weights
  unsigned short* qkvI = (unsigned short*)d_ws;
  unsigned short* wat2 = qkvI + (size_t)N_ * RW;
  unsigned short* wbt2 = wat2 + (size_t)3 * 64 * 512;

  prep_kernel<<<(3 * 64 * 512 + 3 * 32 * 512) / 256, 256, 0, stream>>>(
      W1a, W1b, W2a, W2b, W3a, W3b, wat2, wbt2);
  proj_kernel<<<N_ / MT, 256, 0, stream>>>(E, wat2, wbt2, qkvI);
  agg_kernel<<<B_ / 4, 256, 0, stream>>>(nbr, qkvI, out);
}

// Round 6
// 235.525 us; speedup vs baseline: 1.0248x; 1.0036x over previous
//
#include <hip/hip_runtime.h>
#include <hip/hip_bf16.h>

// Problem constants (reference: B,K,N,F,H = 20000,10,100000,256,128)
constexpr int B_ = 20000;
constexpr int K_ = 10;
constexpr int N_ = 100000;
constexpr int F_ = 256;
constexpr int H_ = 128;
constexpr int RW = 3 * H_;  // interleaved qkv row width (384 ushorts = 768 B)

typedef __attribute__((ext_vector_type(8))) short bf16x8;
typedef __attribute__((ext_vector_type(4))) float f32x4;
typedef __attribute__((ext_vector_type(4))) unsigned short ushort4v;

__device__ __forceinline__ unsigned short f2bf(float x) {
  unsigned int u = __builtin_bit_cast(unsigned int, x);
  unsigned int r = u + 0x7fffu + ((u >> 16) & 1u);
  return (unsigned short)(r >> 16);
}

__device__ __forceinline__ float bf2f(unsigned int u16) {
  return __builtin_bit_cast(float, u16 << 16);
}

// RNE pack of two f32 -> 2xbf16 in one dword (lo -> [15:0], hi -> [31:16]).
__device__ __forceinline__ unsigned int cvt_pk_bf16(float lo, float hi) {
  unsigned int r;
  asm("v_cvt_pk_bf16_f32 %0, %1, %2" : "=v"(r) : "v"(lo), "v"(hi));
  return r;
}

__device__ __forceinline__ float fast_tanh(float x) {
  float e = __expf(2.0f * x);
  return 1.0f - 2.0f * __builtin_amdgcn_rcpf(e + 1.0f);
}

// LDS-only barrier: waits ONLY lgkmcnt (LDS/SMEM), NOT vmcnt.
// __syncthreads() emits "s_waitcnt vmcnt(0) lgkmcnt(0); s_barrier", which
// drains in-flight L2 weight loads and qkvI stores at every phase edge (the
// m97-style structural stall). No barrier in proj orders any GLOBAL op:
// stage barrier protects xs (LDS), per-p barriers protect ts (LDS). So
// lgkmcnt(0)+s_barrier is sufficient; global loads/stores stay in flight
// across barriers. "memory" clobber pins compiler-side ordering.
__device__ __forceinline__ void lds_barrier() {
  asm volatile("s_waitcnt lgkmcnt(0)\n\ts_barrier" ::: "memory");
}

// ---------------------------------------------------------------------------
// Prep: weights -> fragment-major bf16 layout (proven correct; unchanged).
// wat2 chunks (p, ks∈8, c∈8), 512 bf16 each: elem(lane,j) = Wa_p[32ks+8(lane>>4)+j][16c+(lane&15)]
// wbt2 chunks (p, c2∈8, ks2∈4):              elem(lane,j) = Wb_p[32ks2+8(lane>>4)+j][16c2+(lane&15)]
// ---------------------------------------------------------------------------
__global__ __launch_bounds__(256) void prep_kernel(
    const float* __restrict__ W1a, const float* __restrict__ W1b,
    const float* __restrict__ W2a, const float* __restrict__ W2b,
    const float* __restrict__ W3a, const float* __restrict__ W3b,
    unsigned short* __restrict__ wat2, unsigned short* __restrict__ wbt2) {
  const float* Wa[3] = {W1a, W2a, W3a};
  const float* Wb[3] = {W1b, W2b, W3b};
  int g = blockIdx.x * 256 + threadIdx.x;
  if (g < 3 * 64 * 512) {
    int chunk = g >> 9;
    int e = g & 511;
    int lane = e >> 3, j = e & 7;
    int c = chunk & 7;
    int ks = (chunk >> 3) & 7;
    int p = chunk >> 6;
    int k = 32 * ks + 8 * (lane >> 4) + j;
    int h = 16 * c + (lane & 15);
    wat2[g] = f2bf(Wa[p][k * H_ + h]);
  } else {
    int g2 = g - 3 * 64 * 512;
    int chunk = g2 >> 9;
    int e = g2 & 511;
    int lane = e >> 3, j = e & 7;
    int ks2 = chunk & 3;
    int c2 = (chunk >> 2) & 7;
    int p = chunk >> 5;
    int k = 32 * ks2 + 8 * (lane >> 4) + j;
    int h2 = 16 * c2 + (lane & 15);
    wbt2[g2] = f2bf(Wb[p][k * H_ + h2]);
  }
}

// ---------------------------------------------------------------------------
// Projections — R6: R5 base, ONE change: all 7 __syncthreads() replaced by
// lds_barrier() (lgkmcnt-only). Theory: the vmcnt(0) drain at each
// __syncthreads serialized L2 weight loads + qkvI store-acks into block
// residency (~64k cy observed vs ~11k cy of work; no pipe >25% busy).
// Geometry unchanged: MT=32, 4 waves, 2x2 blocking, 25.6 KB LDS.
// ---------------------------------------------------------------------------
constexpr int MT = 32;
constexpr int XS = F_ + 8;  // 264 shorts = 528 B row stride (2-way max, free)
constexpr int TS = H_ + 8;  // 136 shorts = 272 B row stride

__global__ __launch_bounds__(256) void proj_kernel(
    const float* __restrict__ E,
    const unsigned short* __restrict__ wat2,
    const unsigned short* __restrict__ wbt2,
    unsigned short* __restrict__ qkvI) {
  __shared__ unsigned short xs[MT * XS];  // 16896 B
  __shared__ unsigned short ts[MT * TS];  // 8704 B

  const int tid = threadIdx.x;
  const int lane = tid & 63;
  const int w = tid >> 6;    // 0..3 : owns h-tiles {2w, 2w+1}
  const int l15 = lane & 15;
  const int q = lane >> 4;
  const int row0 = blockIdx.x * MT;

  // ---- stage X tile (fp32 -> bf16), coalesced; clamp OOB rows (insurance)
  {
    const float4* Eg = (const float4*)E;
#pragma unroll
    for (int it = 0; it < 8; ++it) {
      int i = tid + 256 * it;
      int r = i >> 6;
      int c4 = i & 63;
      int row = row0 + r;
      if (row >= N_) row = N_ - 1;
      float4 v = Eg[(size_t)row * (F_ / 4) + c4];
      unsigned int lo = cvt_pk_bf16(v.x, v.y);
      unsigned int hi = cvt_pk_bf16(v.z, v.w);
      *(uint2*)&xs[r * XS + c4 * 4] = make_uint2(lo, hi);
    }
  }
  lds_barrier();

  for (int p = 0; p < 3; ++p) {
    const unsigned short* __restrict__ wa = wat2 + p * (64 * 512);
    const unsigned short* __restrict__ wb = wbt2 + p * (32 * 512);

    // ---- preload layer-1 weight fragments (compiler may re-schedule; the
    // lgkm-only barriers now let these stay in flight across phase edges).
    bf16x8 af[2][8];
#pragma unroll
    for (int ks = 0; ks < 8; ++ks) {
      af[0][ks] = *(const bf16x8*)&wa[(ks * 8 + 2 * w) * 512 + lane * 8];
      af[1][ks] = *(const bf16x8*)&wa[(ks * 8 + 2 * w + 1) * 512 + lane * 8];
    }

    // ---- layer 1, K=256. acc[i][j]: h-tile 2w+i, node-tile j.
    f32x4 acc[2][2];
#pragma unroll
    for (int i = 0; i < 2; ++i)
#pragma unroll
      for (int j = 0; j < 2; ++j) acc[i][j] = (f32x4)0.0f;

#pragma unroll
    for (int ks = 0; ks < 8; ++ks) {
      bf16x8 bx0 = *(const bf16x8*)&xs[(l15)*XS + 32 * ks + 8 * q];
      bf16x8 bx1 = *(const bf16x8*)&xs[(16 + l15) * XS + 32 * ks + 8 * q];
      acc[0][0] = __builtin_amdgcn_mfma_f32_16x16x32_bf16(af[0][ks], bx0, acc[0][0], 0, 0, 0);
      acc[0][1] = __builtin_amdgcn_mfma_f32_16x16x32_bf16(af[0][ks], bx1, acc[0][1], 0, 0, 0);
      acc[1][0] = __builtin_amdgcn_mfma_f32_16x16x32_bf16(af[1][ks], bx0, acc[1][0], 0, 0, 0);
      acc[1][1] = __builtin_amdgcn_mfma_f32_16x16x32_bf16(af[1][ks], bx1, acc[1][1], 0, 0, 0);
    }

    // ---- issue layer-2 weight preload NOW: lands during tanh + barriers.
    bf16x8 ab[2][4];
#pragma unroll
    for (int ks2 = 0; ks2 < 4; ++ks2) {
      ab[0][ks2] = *(const bf16x8*)&wb[((2 * w) * 4 + ks2) * 512 + lane * 8];
      ab[1][ks2] = *(const bf16x8*)&wb[((2 * w + 1) * 4 + ks2) * 512 + lane * 8];
    }

    // ---- tanh + pack -> ts[node][h] via 8B LDS writes (C->A transpose)
    lds_barrier();  // prior p's ts reads complete (LDS-only ordering)
#pragma unroll
    for (int i = 0; i < 2; ++i)
#pragma unroll
      for (int j = 0; j < 2; ++j) {
        unsigned int lo = cvt_pk_bf16(fast_tanh(acc[i][j][0]), fast_tanh(acc[i][j][1]));
        unsigned int hi = cvt_pk_bf16(fast_tanh(acc[i][j][2]), fast_tanh(acc[i][j][3]));
        // value (h = 16*(2w+i)+4q+r, node = 16j+l15)
        *(uint2*)&ts[(16 * j + l15) * TS + 16 * (2 * w + i) + 4 * q] =
            make_uint2(lo, hi);
      }
    lds_barrier();

    // ---- layer 2, K=128 (weights already in registers)
    f32x4 ac2[2][2];
#pragma unroll
    for (int i = 0; i < 2; ++i)
#pragma unroll
      for (int j = 0; j < 2; ++j) ac2[i][j] = (f32x4)0.0f;

#pragma unroll
    for (int ks2 = 0; ks2 < 4; ++ks2) {
      bf16x8 bt0 = *(const bf16x8*)&ts[(l15)*TS + 32 * ks2 + 8 * q];
      bf16x8 bt1 = *(const bf16x8*)&ts[(16 + l15) * TS + 32 * ks2 + 8 * q];
      ac2[0][0] = __builtin_amdgcn_mfma_f32_16x16x32_bf16(ab[0][ks2], bt0, ac2[0][0], 0, 0, 0);
      ac2[0][1] = __builtin_amdgcn_mfma_f32_16x16x32_bf16(ab[0][ks2], bt1, ac2[0][1], 0, 0, 0);
      ac2[1][0] = __builtin_amdgcn_mfma_f32_16x16x32_bf16(ab[1][ks2], bt0, ac2[1][0], 0, 0, 0);
      ac2[1][1] = __builtin_amdgcn_mfma_f32_16x16x32_bf16(ab[1][ks2], bt1, ac2[1][1], 0, 0, 0);
    }

    // ---- store qkv^T: col=node, rows h2 consecutive -> 8B contiguous stores
    //      (stores stay in flight across the next p's lgkm-only barriers)
#pragma unroll
    for (int i = 0; i < 2; ++i)
#pragma unroll
      for (int j = 0; j < 2; ++j) {
        int n = row0 + 16 * j + l15;
        if (n < N_) {
          unsigned int lo = cvt_pk_bf16(ac2[i][j][0], ac2[i][j][1]);
          unsigned int hi = cvt_pk_bf16(ac2[i][j][2], ac2[i][j][3]);
          *(uint2*)&qkvI[(size_t)n * RW + p * H_ + 16 * (2 * w + i) + 4 * q] =
              make_uint2(lo, hi);
        }
      }
  }
}

// ---------------------------------------------------------------------------
// Phase 2: one WAVE per batch node, gathering from interleaved qkvI
// (768 B contiguous per neighbor). No LDS, no barriers. (Unchanged.)
// ---------------------------------------------------------------------------
__global__ __launch_bounds__(256) void agg_kernel(
    const int* __restrict__ nbr,
    const unsigned short* __restrict__ qkvI,
    float* __restrict__ out) {
  const int lane = threadIdx.x & 63;
  const int wv = threadIdx.x >> 6;
  const int b = blockIdx.x * 4 + wv;
  const int l15 = lane & 15;
  const int kg = lane >> 4;

  const int ni = nbr[b * K_ + (l15 < K_ ? l15 : 0)];
  const size_t nbase = (size_t)ni * RW;

  // scores[i][j] = q_i . k_j
  f32x4 sc = (f32x4)0.0f;
#pragma unroll
  for (int k = 0; k < 4; ++k) {
    const int off = k * 32 + kg * 8;
    bf16x8 qf = *(const bf16x8*)&qkvI[nbase + off];
    bf16x8 kf = *(const bf16x8*)&qkvI[nbase + H_ + off];
    sc = __builtin_amdgcn_mfma_f32_16x16x32_bf16(qf, kf, sc, 0, 0, 0);
  }

  if (l15 >= K_) {
#pragma unroll
    for (int r = 0; r < 4; ++r) sc[r] = -3.0e38f;
  }

  float mx[4], e[4], sm[4];
#pragma unroll
  for (int r = 0; r < 4; ++r) mx[r] = sc[r];
#pragma unroll
  for (int st = 1; st < 16; st <<= 1)
#pragma unroll
    for (int r = 0; r < 4; ++r) mx[r] = fmaxf(mx[r], __shfl_xor(mx[r], st, 16));
#pragma unroll
  for (int r = 0; r < 4; ++r) { e[r] = __expf(sc[r] - mx[r]); sm[r] = e[r]; }
#pragma unroll
  for (int st = 1; st < 16; st <<= 1)
#pragma unroll
    for (int r = 0; r < 4; ++r) sm[r] += __shfl_xor(sm[r], st, 16);

  float cs = 0.0f;
#pragma unroll
  for (int r = 0; r < 4; ++r) {
    float a = e[r] * __builtin_amdgcn_rcpf(sm[r]);
    if (kg * 4 + r >= K_) a = 0.0f;
    cs += a;
  }
  cs += __shfl_xor(cs, 16, 64);
  cs += __shfl_xor(cs, 32, 64);

  float o0 = 0.0f, o1 = 0.0f;
#pragma unroll
  for (int j = 0; j < K_; ++j) {
    const float cj = __shfl(cs, j, 64);
    const int nj = __shfl(ni, j, 64);
    const unsigned int v2 =
        *(const unsigned int*)&qkvI[(size_t)nj * RW + 2 * H_ + 2 * lane];
    o0 = fmaf(cj, bf2f(v2 & 0xffffu), o0);
    o1 = fmaf(cj, bf2f(v2 >> 16), o1);
  }
  *(float2*)&out[(size_t)b * H_ + 2 * lane] = make_float2(o0, o1);
}

extern "C" void kernel_launch(void* const* d_in, const int* in_sizes, int n_in,
                              void* d_out, int out_size, void* d_ws, size_t ws_size,
                              hipStream_t stream) {
  const int* nbr = (const int*)d_in[0];
  const float* E = (const float*)d_in[1];
  const float* W1a = (const float*)d_in[2];
  const float* W1b = (const float*)d_in[3];
  const float* W2a = (const float*)d_in[4];
  const float* W2b = (const float*)d_in[5];
  const float* W3a = (const float*)d_in[6];
  const float* W3b = (const float*)d_in[7];
  float* out = (float*)d_out;

  // workspace: qkvI [N][384] bf16 interleaved = 76.8 MB, then frag-major weights
  unsigned short* qkvI = (unsigned short*)d_ws;
  unsigned short* wat2 = qkvI + (size_t)N_ * RW;
  unsigned short* wbt2 = wat2 + (size_t)3 * 64 * 512;

  prep_kernel<<<(3 * 64 * 512 + 3 * 32 * 512) / 256, 256, 0, stream>>>(
      W1a, W1b, W2a, W2b, W3a, W3b, wat2, wbt2);
  proj_kernel<<<N_ / MT, 256, 0, stream>>>(E, wat2, wbt2, qkvI);
  agg_kernel<<<B_ / 4, 256, 0, stream>>>(nbr, qkvI, out);
}